// Round 1
// baseline (141.078 us; speedup 1.0000x reference)
//
#include <hip/hip_runtime.h>

#define BTOT 1000000
#define NCHUNK (BTOT / 64)   // 15625 chunks of 64 elements

typedef _Float16 f16;
typedef f16 f16x2 __attribute__((ext_vector_type(2)));
typedef f16 f16x8 __attribute__((ext_vector_type(8)));
typedef float f32x4 __attribute__((ext_vector_type(4)));

__global__ __launch_bounds__(256, 2) void netc_kernel(
    const float* __restrict__ x,  const float* __restrict__ y,
    const float* __restrict__ ex, const float* __restrict__ ey,
    const float* __restrict__ W1, const float* __restrict__ b1,
    const float* __restrict__ W2, const float* __restrict__ b2,
    const float* __restrict__ W3,
    float* __restrict__ out)
{
    const int tid  = threadIdx.x;
    const int lane = tid & 63;
    const int wv   = tid >> 6;
    const int quad = lane >> 4;
    const int nl   = lane & 15;

    __shared__ float lds_h1[4 * 64];

    // ---------- u(target) in fp32, once per wave (b3 cancels) ----------
    const float T = 6.2562059f; // 0.62562059 * 10
    {
        float h1t = fmaxf(0.f, W1[2 * lane] * T + W1[2 * lane + 1] * T + b1[lane]);
        lds_h1[wv * 64 + lane] = h1t;
    }
    __syncthreads();
    float u_tgt;
    {
        float h2t = b2[lane];
        #pragma unroll
        for (int k = 0; k < 64; ++k)
            h2t = fmaf(W2[lane * 64 + k], lds_h1[wv * 64 + k], h2t);
        float p = fmaxf(0.f, h2t) * W3[lane];
        #pragma unroll
        for (int m = 1; m < 64; m <<= 1) p += __shfl_xor(p, m, 64);
        u_tgt = p;
    }

    // ---------- per-lane constant weights ----------
    // W1/b1 packed f16: half0 -> k0 = quad*8+j (K-step 0), half1 -> k0+32 (K-step 1)
    f16x2 w1a[8], w1b[8], b1p[8];
    #pragma unroll
    for (int j = 0; j < 8; ++j) {
        int k0 = quad * 8 + j, k1 = k0 + 32;
        w1a[j] = f16x2{(f16)W1[2 * k0],     (f16)W1[2 * k1]};
        w1b[j] = f16x2{(f16)W1[2 * k0 + 1], (f16)W1[2 * k1 + 1]};
        b1p[j] = f16x2{(f16)b1[k0],         (f16)b1[k1]};
    }
    // W2 B-fragments: b[n][ks][j] = W2[n*16+nl][ks*32 + quad*8 + j]
    f16x8 bfrag[4][2];
    #pragma unroll
    for (int n = 0; n < 4; ++n)
        #pragma unroll
        for (int ks = 0; ks < 2; ++ks) {
            const float* src = W2 + (n * 16 + nl) * 64 + ks * 32 + quad * 8;
            f16x8 f;
            #pragma unroll
            for (int j = 0; j < 8; ++j) f[j] = (f16)src[j];
            bfrag[n][ks] = f;
        }
    float w3v[4], b2v[4];
    #pragma unroll
    for (int n = 0; n < 4; ++n) { w3v[n] = W3[n * 16 + nl]; b2v[n] = b2[n * 16 + nl]; }

    const f16x2 zero2 = {(f16)0.f, (f16)0.f};
    const int nwaves = (gridDim.x * blockDim.x) >> 6;
    int chunk = (blockIdx.x << 2) + wv;

    // software-pipelined element loads (lane <-> element chunk*64+lane)
    float cx = 0.f, cy = 0.f, cex = 0.f, cey = 0.f;
    if (chunk < NCHUNK) {
        int base = chunk * 64 + lane;
        cx = x[base]; cy = y[base]; cex = ex[base]; cey = ey[base];
    }

    for (; chunk < NCHUNK; chunk += nwaves) {
        int nxt = chunk + nwaves;
        float nx_ = 0.f, ny_ = 0.f, nex_ = 0.f, ney_ = 0.f;
        if (nxt < NCHUNK) {
            int nb = nxt * 64 + lane;
            nx_ = x[nb]; ny_ = y[nb]; nex_ = ex[nb]; ney_ = ey[nb];
        }

        float av = cx + cex, bv = cy + cey;

        // accumulators pre-loaded with b2 (column-constant)
        f32x4 acc[4][4];
        #pragma unroll
        for (int t = 0; t < 4; ++t)
            #pragma unroll
            for (int n = 0; n < 4; ++n)
                acc[t][n] = f32x4{b2v[n], b2v[n], b2v[n], b2v[n]};

        #pragma unroll
        for (int t = 0; t < 4; ++t) {
            // inputs for element m = nl of M-tile t
            float at = __shfl(av, t * 16 + nl, 64);
            float bt = __shfl(bv, t * 16 + nl, 64);
            f16 ah = (f16)at, bh = (f16)bt;
            f16x2 a2 = {ah, ah};
            f16x2 bb = {bh, bh};
            // layer 1 in packed f16: both K-steps at once
            f16x8 fa0, fa1;
            #pragma unroll
            for (int j = 0; j < 8; ++j) {
                f16x2 h = a2 * w1a[j] + (bb * w1b[j] + b1p[j]);
                h = __builtin_elementwise_max(h, zero2);
                fa0[j] = h[0];
                fa1[j] = h[1];
            }
            #pragma unroll
            for (int n = 0; n < 4; ++n) {
                acc[t][n] = __builtin_amdgcn_mfma_f32_16x16x32_f16(fa0, bfrag[n][0], acc[t][n], 0, 0, 0);
                acc[t][n] = __builtin_amdgcn_mfma_f32_16x16x32_f16(fa1, bfrag[n][1], acc[t][n], 0, 0, 0);
            }
        }

        // ---------- epilogue: u per element ----------
        // uu[t][r] = sum_n relu(h2)*w3 for element t*16 + quad*4 + r (valid in all 16 lanes of quad)
        float uu[4][4];
        #pragma unroll
        for (int t = 0; t < 4; ++t)
            #pragma unroll
            for (int r = 0; r < 4; ++r) {
                float p = 0.f;
                #pragma unroll
                for (int n = 0; n < 4; ++n)
                    p = fmaf(fmaxf(acc[t][n][r], 0.f), w3v[n], p);
                #pragma unroll
                for (int m = 1; m < 16; m <<= 1) p += __shfl_xor(p, m, 64);
                uu[t][r] = p;
            }

        // sender lane s (p=s&15) provides uu[p>>2][p&3]
        float ur[4];
        #pragma unroll
        for (int t = 0; t < 4; ++t) {
            float v01 = (nl & 1) ? uu[t][1] : uu[t][0];
            float v23 = (nl & 1) ? uu[t][3] : uu[t][2];
            ur[t] = (nl & 2) ? v23 : v01;
        }
        float s01  = (nl & 4) ? ur[1] : ur[0];
        float s23  = (nl & 4) ? ur[3] : ur[2];
        float send = (nl & 8) ? s23 : s01;
        // receiver: element e = lane -> t'=quad, q'=nl>>2, r'=nl&3; sender = q'*16 + quad*4 + (nl&3)
        int srcLane = ((nl >> 2) << 4) + quad * 4 + (nl & 3);
        float u_e = __shfl(send, srcLane, 64) - u_tgt;

        // ---------- Hill kinetics (fp32) ----------
        float xs = cx * 0.1f, ys = cy * 0.1f;
        float x2 = xs * xs, y2 = ys * ys;
        float invx = __fdividef(1.0f, 0.25f + x2);
        float invy = __fdividef(1.0f, 0.25f + y2);
        float hx = x2 * invx, hy = y2 * invy;
        float gx = 0.25f * invx, gy = 0.25f * invy;
        float dx = 10.f * (fmaf(u_e, hx, hx) + 0.2f * gy - 1.1f * xs);
        float dy = 10.f * (hy + 0.2f * gx - 1.1f * ys);

        int e = chunk * 64 + lane;
        out[e]            = dx;
        out[BTOT + e]     = dy;
        out[2 * BTOT + e] = -dx;
        out[3 * BTOT + e] = -dy;

        cx = nx_; cy = ny_; cex = nex_; cey = ney_;
    }
}

extern "C" void kernel_launch(void* const* d_in, const int* in_sizes, int n_in,
                              void* d_out, int out_size, void* d_ws, size_t ws_size,
                              hipStream_t stream) {
    const float* x  = (const float*)d_in[0];
    const float* y  = (const float*)d_in[1];
    const float* ex = (const float*)d_in[2];
    const float* ey = (const float*)d_in[3];
    const float* W1 = (const float*)d_in[4];
    const float* b1 = (const float*)d_in[5];
    const float* W2 = (const float*)d_in[6];
    const float* b2 = (const float*)d_in[7];
    const float* W3 = (const float*)d_in[8];
    float* out = (float*)d_out;
    // 512 blocks x 256 threads = 2048 waves = exactly 2 waves/SIMD resident
    netc_kernel<<<512, 256, 0, stream>>>(x, y, ex, ey, W1, b1, W2, b2, W3, out);
}

// Round 2
// 128.820 us; speedup vs baseline: 1.0952x; 1.0952x over previous
//
#include <hip/hip_runtime.h>

#define BTOT 1000000
#define NCHUNK (BTOT / 64)   // 15625 chunks of 64 elements

typedef _Float16 f16;
typedef f16 f16x2 __attribute__((ext_vector_type(2)));
typedef f16 f16x8 __attribute__((ext_vector_type(8)));
typedef float f32x4 __attribute__((ext_vector_type(4)));

// 16-lane-row rotate-and-add via DPP (VALU pipe, no LDS traffic).
// After ror8,ror4,ror2,ror1 all 16 lanes of each row hold the row sum.
template<int CTRL>
__device__ __forceinline__ float dpp_add(float v) {
    int pv = __builtin_amdgcn_update_dpp(0, __builtin_bit_cast(int, v),
                                         CTRL, 0xF, 0xF, true);
    return v + __builtin_bit_cast(float, pv);
}

__global__ __launch_bounds__(256, 3) void netc_kernel(
    const float* __restrict__ x,  const float* __restrict__ y,
    const float* __restrict__ ex, const float* __restrict__ ey,
    const float* __restrict__ W1, const float* __restrict__ b1,
    const float* __restrict__ W2, const float* __restrict__ b2,
    const float* __restrict__ W3,
    float* __restrict__ out)
{
    const int tid  = threadIdx.x;
    const int lane = tid & 63;
    const int wv   = tid >> 6;
    const int quad = lane >> 4;
    const int nl   = lane & 15;

    __shared__ float lds_h1[4 * 64];

    // ---------- u(target) in fp32, once per wave (b3 cancels) ----------
    const float T = 6.2562059f; // 0.62562059 * 10
    {
        float h1t = fmaxf(0.f, W1[2 * lane] * T + W1[2 * lane + 1] * T + b1[lane]);
        lds_h1[wv * 64 + lane] = h1t;
    }
    __syncthreads();
    float u_tgt;
    {
        float h2t = b2[lane];
        #pragma unroll
        for (int k = 0; k < 64; ++k)
            h2t = fmaf(W2[lane * 64 + k], lds_h1[wv * 64 + k], h2t);
        float p = fmaxf(0.f, h2t) * W3[lane];
        #pragma unroll
        for (int m = 1; m < 64; m <<= 1) p += __shfl_xor(p, m, 64);
        u_tgt = p;
    }

    // ---------- per-lane constant weights ----------
    // Layer-1 weights packed so the f16x2 results ARE the A-fragment:
    // pair i covers k = kp(i), kp(i)+1 with kp(i) = (i<4 ? quad*8+2i : 32+quad*8+2(i-4)).
    // Fragment f16x8 index j = 2*(i%4)+b  ->  k = quad*8 + j (+32 for step 1). No repack.
    f16x2 w1a[8], w1b[8], b1p[8];
    #pragma unroll
    for (int i = 0; i < 8; ++i) {
        int kk = (i < 4) ? (quad * 8 + 2 * i) : (32 + quad * 8 + 2 * (i - 4));
        w1a[i] = f16x2{(f16)W1[2 * kk],     (f16)W1[2 * kk + 2]};
        w1b[i] = f16x2{(f16)W1[2 * kk + 1], (f16)W1[2 * kk + 3]};
        b1p[i] = f16x2{(f16)b1[kk],         (f16)b1[kk + 1]};
    }
    // W2 B-fragments: bfrag[n][ks][j] = W2[n*16+nl][ks*32 + quad*8 + j]
    f16x8 bfrag[4][2];
    #pragma unroll
    for (int n = 0; n < 4; ++n)
        #pragma unroll
        for (int ks = 0; ks < 2; ++ks) {
            const float* src = W2 + (n * 16 + nl) * 64 + ks * 32 + quad * 8;
            f16x8 f;
            #pragma unroll
            for (int j = 0; j < 8; ++j) f[j] = (f16)src[j];
            bfrag[n][ks] = f;
        }
    float w3v[4], b2v[4];
    #pragma unroll
    for (int n = 0; n < 4; ++n) { w3v[n] = W3[n * 16 + nl]; b2v[n] = b2[n * 16 + nl]; }

    const f16x2 zero2 = {(f16)0.f, (f16)0.f};
    const int nwaves = (gridDim.x * blockDim.x) >> 6;
    int chunk = (blockIdx.x << 2) + wv;

    // Gather loads in MFMA A-layout: lane reads element chunk*64 + t*16 + nl
    // (4-way broadcast across quads, L1-served). Lane-layout values for the
    // Hill math are recovered with a 3-cndmask quad-select (t == quad).
    float xg[4], yg[4], exg[4], eyg[4];
    if (chunk < NCHUNK) {
        #pragma unroll
        for (int t = 0; t < 4; ++t) {
            int a = chunk * 64 + t * 16 + nl;
            xg[t] = x[a]; yg[t] = y[a]; exg[t] = ex[a]; eyg[t] = ey[a];
        }
    }

    for (; chunk < NCHUNK; chunk += nwaves) {
        // current-iter derived values
        float ag[4], bg[4];
        #pragma unroll
        for (int t = 0; t < 4; ++t) { ag[t] = xg[t] + exg[t]; bg[t] = yg[t] + eyg[t]; }
        float cx0 = (quad & 1) ? xg[1] : xg[0];
        float cx1 = (quad & 1) ? xg[3] : xg[2];
        float cx  = (quad & 2) ? cx1 : cx0;
        float cy0 = (quad & 1) ? yg[1] : yg[0];
        float cy1 = (quad & 1) ? yg[3] : yg[2];
        float cy  = (quad & 2) ? cy1 : cy0;

        // prefetch next iter
        int nxt = chunk + nwaves;
        float nx_[4] = {0,0,0,0}, ny_[4] = {0,0,0,0}, nex_[4] = {0,0,0,0}, ney_[4] = {0,0,0,0};
        if (nxt < NCHUNK) {
            #pragma unroll
            for (int t = 0; t < 4; ++t) {
                int a = nxt * 64 + t * 16 + nl;
                nx_[t] = x[a]; ny_[t] = y[a]; nex_[t] = ex[a]; ney_[t] = ey[a];
            }
        }

        // accumulators pre-loaded with b2 (column-constant)
        f32x4 acc[4][4];
        #pragma unroll
        for (int t = 0; t < 4; ++t)
            #pragma unroll
            for (int n = 0; n < 4; ++n)
                acc[t][n] = f32x4{b2v[n], b2v[n], b2v[n], b2v[n]};

        #pragma unroll
        for (int t = 0; t < 4; ++t) {
            f16 ah = (f16)ag[t], bh = (f16)bg[t];
            f16x2 a2 = {ah, ah};
            f16x2 bb = {bh, bh};
            union { f16x2 h2[8]; f16x8 fr[2]; } u;
            #pragma unroll
            for (int i = 0; i < 8; ++i) {
                f16x2 h = a2 * w1a[i] + (bb * w1b[i] + b1p[i]);
                u.h2[i] = __builtin_elementwise_max(h, zero2);
            }
            #pragma unroll
            for (int n = 0; n < 4; ++n) {
                acc[t][n] = __builtin_amdgcn_mfma_f32_16x16x32_f16(u.fr[0], bfrag[n][0], acc[t][n], 0, 0, 0);
                acc[t][n] = __builtin_amdgcn_mfma_f32_16x16x32_f16(u.fr[1], bfrag[n][1], acc[t][n], 0, 0, 0);
            }
        }

        // ---------- epilogue: layer 3 via DPP row reductions ----------
        // uu[t][r] on lane = u for element t*16 + quad*4 + r (valid in all 16 row lanes)
        float uu[4][4];
        #pragma unroll
        for (int t = 0; t < 4; ++t)
            #pragma unroll
            for (int r = 0; r < 4; ++r) {
                float p = 0.f;
                #pragma unroll
                for (int n = 0; n < 4; ++n)
                    p = fmaf(fmaxf(acc[t][n][r], 0.f), w3v[n], p);
                p = dpp_add<0x128>(p);  // row_ror:8
                p = dpp_add<0x124>(p);  // row_ror:4
                p = dpp_add<0x122>(p);  // row_ror:2
                p = dpp_add<0x121>(p);  // row_ror:1
                uu[t][r] = p;
            }

        // sender lane s (p=s&15) provides uu[p>>2][p&3]
        float ur[4];
        #pragma unroll
        for (int t = 0; t < 4; ++t) {
            float v01 = (nl & 1) ? uu[t][1] : uu[t][0];
            float v23 = (nl & 1) ? uu[t][3] : uu[t][2];
            ur[t] = (nl & 2) ? v23 : v01;
        }
        float s01  = (nl & 4) ? ur[1] : ur[0];
        float s23  = (nl & 4) ? ur[3] : ur[2];
        float send = (nl & 8) ? s23 : s01;
        // receiver element e = lane: sender = (nl>>2)*16 + quad*4 + (nl&3)
        int srcLane = ((nl >> 2) << 4) + quad * 4 + (nl & 3);
        float u_e = __shfl(send, srcLane, 64) - u_tgt;

        // ---------- Hill kinetics (fp32) ----------
        float xs = cx * 0.1f, ys = cy * 0.1f;
        float x2 = xs * xs, y2 = ys * ys;
        float invx = __fdividef(1.0f, 0.25f + x2);
        float invy = __fdividef(1.0f, 0.25f + y2);
        float hx = x2 * invx, hy = y2 * invy;
        float gx = 0.25f * invx, gy = 0.25f * invy;
        float dx = 10.f * (fmaf(u_e, hx, hx) + 0.2f * gy - 1.1f * xs);
        float dy = 10.f * (hy + 0.2f * gx - 1.1f * ys);

        int e = chunk * 64 + lane;
        out[e]            = dx;
        out[BTOT + e]     = dy;
        out[2 * BTOT + e] = -dx;
        out[3 * BTOT + e] = -dy;

        #pragma unroll
        for (int t = 0; t < 4; ++t) {
            xg[t] = nx_[t]; yg[t] = ny_[t]; exg[t] = nex_[t]; eyg[t] = ney_[t];
        }
    }
}

extern "C" void kernel_launch(void* const* d_in, const int* in_sizes, int n_in,
                              void* d_out, int out_size, void* d_ws, size_t ws_size,
                              hipStream_t stream) {
    const float* x  = (const float*)d_in[0];
    const float* y  = (const float*)d_in[1];
    const float* ex = (const float*)d_in[2];
    const float* ey = (const float*)d_in[3];
    const float* W1 = (const float*)d_in[4];
    const float* b1 = (const float*)d_in[5];
    const float* W2 = (const float*)d_in[6];
    const float* b2 = (const float*)d_in[7];
    const float* W3 = (const float*)d_in[8];
    float* out = (float*)d_out;
    // 1024 blocks x 256 threads = 4096 waves; 3-4 waves/SIMD resident
    netc_kernel<<<1024, 256, 0, stream>>>(x, y, ex, ey, W1, b1, W2, b2, W3, out);
}